// Round 8
// baseline (218.400 us; speedup 1.0000x reference)
//
#include <hip/hip_runtime.h>
#include <hip/hip_bf16.h>
#include <stdint.h>

#define NV   65536   // active voxels
#define KOFF 27      // kernel offsets
#define CIN  128
#define COUT 128
#define NGRP 3       // offset groups (9 offsets each)
#define KPG  9

typedef __bf16 bf16x8 __attribute__((ext_vector_type(8)));
typedef float  f32x4  __attribute__((ext_vector_type(4)));

__device__ __forceinline__ void async_copy16(void* lds, const void* g) {
    __builtin_amdgcn_global_load_lds(
        (const __attribute__((address_space(1))) void*)g,
        (__attribute__((address_space(3))) void*)lds,
        16, 0, 0);
}

// ---- fused prep kernel --------------------------------------------------
// Jobs partitioned by blockIdx range (mutually independent; nbr memset to
// 0xFF by a prior hipMemsetAsync node on the same stream):
//   A [0, 4097)    : features f32 -> bf16 x8 (row NV zeroed)
//   B [4097, 4313) : weight f32 [K][cin][cout] -> bf16 fragment-major,
//                    s-major for the ks-ring (s = k*4+ks in [0,108)):
//                    chunk c = s*512 + wv*128 + nt*64 + lane, holding
//                    B[cout=wv*32+nt*16+(lane&15)][cin=ks*32+(lane>>4)*8+j]
//   S [4313, 6041) : rulebook scatter x4: nbr[k][out[p]] = in[p]
#define JOB_A_BLOCKS 4097
#define JOB_B_BLOCKS 216    // 108*512 chunks / 256
#define JOB_S_BLOCKS 1728   // 27*65536/4/256

__global__ void k_prep_all(const float* __restrict__ f,
                           uint4* __restrict__ fb4,
                           const float* __restrict__ w,
                           uint4* __restrict__ wfrag4,
                           const int4* __restrict__ in4,
                           const int4* __restrict__ out4,
                           int* __restrict__ nbr) {
    const int b = blockIdx.x;
    const int t = threadIdx.x;
    if (b < JOB_A_BLOCKS) {
        // ---- job A: feature cast x8 ----
        int i = b * 256 + t;
        int total8  = (NV + 1) * CIN / 8;
        int nvalid8 = NV * CIN / 8;
        if (i >= total8) return;
        union { uint4 u; __hip_bfloat16 h[8]; } p;
        if (i < nvalid8) {
            const float4* f4 = (const float4*)f;
            float4 a = f4[i * 2];
            float4 c = f4[i * 2 + 1];
            p.h[0] = __float2bfloat16(a.x);
            p.h[1] = __float2bfloat16(a.y);
            p.h[2] = __float2bfloat16(a.z);
            p.h[3] = __float2bfloat16(a.w);
            p.h[4] = __float2bfloat16(c.x);
            p.h[5] = __float2bfloat16(c.y);
            p.h[6] = __float2bfloat16(c.z);
            p.h[7] = __float2bfloat16(c.w);
        } else {
            p.u = make_uint4(0, 0, 0, 0);   // zero row NV
        }
        fb4[i] = p.u;
    } else if (b < JOB_A_BLOCKS + JOB_B_BLOCKS) {
        // ---- job B: weight -> s-major fragment layout (1x4 wave) ----
        int c    = (b - JOB_A_BLOCKS) * 256 + t;   // chunk index
        int lane = c & 63;
        int nt   = (c >> 6) & 1;
        int wv   = (c >> 7) & 3;
        int s    = c >> 9;
        int ks   = s & 3;
        int k    = s >> 2;
        int cout = wv * 32 + nt * 16 + (lane & 15);
        int cin0 = ks * 32 + (lane >> 4) * 8;
        const float* wk = w + k * 16384;
        union { uint4 u; __hip_bfloat16 h[8]; } p;
        #pragma unroll
        for (int j = 0; j < 8; ++j)
            p.h[j] = __float2bfloat16(wk[(cin0 + j) * 128 + cout]);
        wfrag4[c] = p.u;
    } else {
        // ---- job S: rulebook scatter x4 (out_idx sorted -> near-coalesced) ----
        int i = (b - JOB_A_BLOCKS - JOB_B_BLOCKS) * 256 + t;
        int k = i >> 14;                   // / (NV/4)
        int4 ii = in4[i];
        int4 oo = out4[i];
        int* nb = nbr + k * (NV + 1);      // slot NV = dummy for padded pairs
        nb[oo.x] = ii.x;
        nb[oo.y] = ii.y;
        nb[oo.z] = ii.z;
        nb[oo.w] = ii.w;
    }
}

// ---- main gather-GEMM kernel -------------------------------------------
// grid = 1536: block bid handles tile = bid/3 (128 out-rows), offset group
// g = bid%3 (9 offsets). Siblings of a tile are adjacent in dispatch for L2
// feature-window sharing. Single-buffer A (32 KB LDS) -> 3+ blocks/CU with
// __launch_bounds__(256,3); inter-block co-scheduling hides each block's
// stage/barrier stalls. Wave w = all 128 rows x cout slice [w*32, w*32+32).
// B: ks-ring in registers (2x2 uint4 live) loaded during compute — safe now
// because no A-staging is outstanding during the compute phase.
// Groups accumulate into pre-zeroed out via coalesced fp32 atomicAdd;
// bias folded into group 0's accumulator init.
__global__ __launch_bounds__(256, 3)
void sp_conv_main(const __hip_bfloat16* __restrict__ feats,
                  const uint4* __restrict__ wfrag,
                  const int* __restrict__ nbr,
                  const float* __restrict__ bias,
                  float* __restrict__ out) {
    __shared__ unsigned char smA[32768];   // single 32 KB A buffer

    const int t   = threadIdx.x;
    const int bid = blockIdx.x;
    const int g   = bid % NGRP;            // offset group
    const int tb  = bid / NGRP;            // tile index [0,512)
    // XCD swizzle: consecutive 64-tile ranges per XCD for L2 gather locality
    const int tile0 = ((tb & 7) * 64 + (tb >> 3)) * 128;
    const int kbeg  = g * KPG;
    const int send  = (kbeg + KPG) * 4;

    const int w    = t >> 6;
    const int lane = t & 63;
    const int lr   = lane & 15;
    const int quad = lane >> 4;
    const int n0w  = w * 32;

    // staging-side mapping: LDS slot (row = i*16 + t/16, physchunk = t&15)
    // holds global 16B chunk c = (t&15) ^ (row&15)
    const int srow   = t >> 4;
    const int sbyte  = ((t & 15) ^ srow) * 16;

    // accumulators; bias folded into group 0 init
    f32x4 acc[8][2];
    {
        float b0 = (g == 0) ? bias[n0w + lr]      : 0.0f;
        float b1 = (g == 0) ? bias[n0w + 16 + lr] : 0.0f;
        #pragma unroll
        for (int mt = 0; mt < 8; ++mt) {
            acc[mt][0] = (f32x4){b0, b0, b0, b0};
            acc[mt][1] = (f32x4){b1, b1, b1, b1};
        }
    }

    const unsigned char* featsB = (const unsigned char*)feats;

    // nbr rows for kbeg
    int arows[8];
    {
        const int* nbr0 = nbr + kbeg * (NV + 1) + tile0;
        #pragma unroll
        for (int i = 0; i < 8; ++i) arows[i] = nbr0[i * 16 + srow];
    }
    // B ring: group s lives in bb[s&1]; preload s = kbeg*4
    const uint4* wfp = wfrag + w * 128 + lane;
    uint4 bb[2][2];
    #pragma unroll
    for (int nt = 0; nt < 2; ++nt) bb[0][nt] = wfp[(size_t)(kbeg * 4) * 512 + nt * 64];

    for (int k = kbeg; k < kbeg + KPG; ++k) {
        // stage A(k) (global_load_lds x8)
        #pragma unroll
        for (int i = 0; i < 8; ++i) {
            unsigned ar = min((unsigned)arows[i], (unsigned)NV);  // -1 -> zero row
            async_copy16(smA + i * 4096 + t * 16,
                         featsB + (size_t)ar * 256 + sbyte);
        }
        // prefetch nbr rows for k+1 (needed only after next barrier)
        if (k + 1 < kbeg + KPG) {
            const int* nbrn = nbr + (k + 1) * (NV + 1) + tile0;
            #pragma unroll
            for (int i = 0; i < 8; ++i) arows[i] = nbrn[i * 16 + srow];
        }
        __syncthreads();   // drain staging; LDS tile ready

        // compute: B group s feeds ks, group s+1 loads (only vmem in flight)
        #pragma unroll
        for (int ks = 0; ks < 4; ++ks) {
            const int s = k * 4 + ks;
            if (s + 1 < send) {
                const uint4* wfn = wfp + (size_t)(s + 1) * 512;
                #pragma unroll
                for (int nt = 0; nt < 2; ++nt)
                    bb[(ks + 1) & 1][nt] = wfn[nt * 64];
            }
            bf16x8 af[8];
            #pragma unroll
            for (int mt = 0; mt < 8; ++mt) {
                int row = mt * 16 + lr;               // row & 15 == lr
                af[mt] = *(const bf16x8*)(smA + row * 256 +
                                          (((ks * 4 + quad) ^ lr) * 16));
            }
            #pragma unroll
            for (int mt = 0; mt < 8; ++mt)
                #pragma unroll
                for (int nt = 0; nt < 2; ++nt)
                    acc[mt][nt] = __builtin_amdgcn_mfma_f32_16x16x32_bf16(
                        af[mt], *(const bf16x8*)&bb[ks & 1][nt],
                        acc[mt][nt], 0, 0, 0);
        }
        __syncthreads();   // protect smA before next stage overwrites
    }

    // epilogue: C/D layout col = lane&15, row = quad*4 + reg.
    // coalesced fp32 atomicAdd into pre-zeroed out (3 groups accumulate).
    #pragma unroll
    for (int mt = 0; mt < 8; ++mt) {
        #pragma unroll
        for (int nt = 0; nt < 2; ++nt) {
            #pragma unroll
            for (int r = 0; r < 4; ++r) {
                int grow = tile0 + mt * 16 + quad * 4 + r;
                atomicAdd(&out[(size_t)grow * COUT + n0w + nt * 16 + lr],
                          acc[mt][nt][r]);
            }
        }
    }
}

// ---- launch -------------------------------------------------------------

extern "C" void kernel_launch(void* const* d_in, const int* in_sizes, int n_in,
                              void* d_out, int out_size, void* d_ws, size_t ws_size,
                              hipStream_t stream) {
    const float* features = (const float*)d_in[0];   // [N,128] f32
    const float* weight   = (const float*)d_in[1];   // [27,128,128] f32
    const float* bias     = (const float*)d_in[2];   // [128] f32
    const int*   in_idx   = (const int*)d_in[3];     // [27,N] i32
    const int*   out_idx  = (const int*)d_in[4];     // [27,N] i32
    float* out = (float*)d_out;                      // [N,128] f32

    uint8_t* ws = (uint8_t*)d_ws;
    size_t off = 0;
    __hip_bfloat16* feats_bf = (__hip_bfloat16*)(ws + off);       // (N+1)*128*2
    off += (size_t)(NV + 1) * CIN * 2;
    off = (off + 255) & ~(size_t)255;
    uint4* wfrag = (uint4*)(ws + off);                            // 108*512*16 B
    off += (size_t)108 * 512 * 16;
    off = (off + 255) & ~(size_t)255;
    int* nbr = (int*)(ws + off);                                  // 27*(NV+1)*4

    // init nbr to 0xFFFFFFFF (-1 = "no neighbor"; main clamps to zero row)
    hipMemsetAsync(nbr, 0xFF, (size_t)KOFF * (NV + 1) * 4, stream);
    // pre-zero out: groups accumulate atomically
    hipMemsetAsync(out, 0, (size_t)NV * COUT * 4, stream);

    // fused prep: feature cast + weight fragment-permute + rulebook scatter
    k_prep_all<<<JOB_A_BLOCKS + JOB_B_BLOCKS + JOB_S_BLOCKS, 256, 0, stream>>>(
        features, (uint4*)feats_bf, weight, wfrag,
        (const int4*)in_idx, (const int4*)out_idx, nbr);

    // main gather-GEMM: 512 tiles x 3 offset groups
    sp_conv_main<<<512 * NGRP, 256, 0, stream>>>(feats_bf, wfrag, nbr, bias, out);
}

// Round 9
// 162.427 us; speedup vs baseline: 1.3446x; 1.3446x over previous
//
#include <hip/hip_runtime.h>
#include <hip/hip_bf16.h>
#include <stdint.h>

#define NV   65536   // active voxels
#define KOFF 27      // kernel offsets
#define CIN  128
#define COUT 128

typedef __bf16 bf16x8 __attribute__((ext_vector_type(8)));
typedef float  f32x4  __attribute__((ext_vector_type(4)));

__device__ __forceinline__ void async_copy16(void* lds, const void* g) {
    __builtin_amdgcn_global_load_lds(
        (const __attribute__((address_space(1))) void*)g,
        (__attribute__((address_space(3))) void*)lds,
        16, 0, 0);
}

// ---- fused prep kernel --------------------------------------------------
// Jobs partitioned by blockIdx range (mutually independent; nbr memset to
// 0xFF by a prior hipMemsetAsync node on the same stream):
//   A [0, 4097)    : features f32 -> bf16 x8 (row NV zeroed)
//   B [4097, 4313) : weight f32 [K][cin][cout] -> bf16 fragment-major for the
//                    2x2 wave layout, s-major (s = k*4+ks in [0,108)):
//                    chunk c = s*512 + wh*256 + nt*64 + lane, holding
//                    B[cout=wh*64+nt*16+(lane&15)][cin=ks*32+(lane>>4)*8+j]
//   S [4313, 6041) : rulebook scatter x4: nbr[k][out[p]] = in[p]
#define JOB_A_BLOCKS 4097
#define JOB_B_BLOCKS 216    // 108*512 chunks / 256
#define JOB_S_BLOCKS 1728   // 27*65536/4/256

__global__ void k_prep_all(const float* __restrict__ f,
                           uint4* __restrict__ fb4,
                           const float* __restrict__ w,
                           uint4* __restrict__ wfrag4,
                           const int4* __restrict__ in4,
                           const int4* __restrict__ out4,
                           int* __restrict__ nbr) {
    const int b = blockIdx.x;
    const int t = threadIdx.x;
    if (b < JOB_A_BLOCKS) {
        // ---- job A: feature cast x8 ----
        int i = b * 256 + t;
        int total8  = (NV + 1) * CIN / 8;
        int nvalid8 = NV * CIN / 8;
        if (i >= total8) return;
        union { uint4 u; __hip_bfloat16 h[8]; } p;
        if (i < nvalid8) {
            const float4* f4 = (const float4*)f;
            float4 a = f4[i * 2];
            float4 c = f4[i * 2 + 1];
            p.h[0] = __float2bfloat16(a.x);
            p.h[1] = __float2bfloat16(a.y);
            p.h[2] = __float2bfloat16(a.z);
            p.h[3] = __float2bfloat16(a.w);
            p.h[4] = __float2bfloat16(c.x);
            p.h[5] = __float2bfloat16(c.y);
            p.h[6] = __float2bfloat16(c.z);
            p.h[7] = __float2bfloat16(c.w);
        } else {
            p.u = make_uint4(0, 0, 0, 0);   // zero row NV
        }
        fb4[i] = p.u;
    } else if (b < JOB_A_BLOCKS + JOB_B_BLOCKS) {
        // ---- job B: weight -> s-major fragment layout (2x2 wave) ----
        int c    = (b - JOB_A_BLOCKS) * 256 + t;   // chunk index
        int lane = c & 63;
        int nt   = (c >> 6) & 3;
        int wh   = (c >> 8) & 1;
        int s    = c >> 9;
        int ks   = s & 3;
        int k    = s >> 2;
        int cout = wh * 64 + nt * 16 + (lane & 15);
        int cin0 = ks * 32 + (lane >> 4) * 8;
        const float* wk = w + k * 16384;
        union { uint4 u; __hip_bfloat16 h[8]; } p;
        #pragma unroll
        for (int j = 0; j < 8; ++j)
            p.h[j] = __float2bfloat16(wk[(cin0 + j) * 128 + cout]);
        wfrag4[c] = p.u;
    } else {
        // ---- job S: rulebook scatter x4 (out_idx sorted -> near-coalesced) ----
        int i = (b - JOB_A_BLOCKS - JOB_B_BLOCKS) * 256 + t;
        int k = i >> 14;                   // / (NV/4)
        int4 ii = in4[i];
        int4 oo = out4[i];
        int* nb = nbr + k * (NV + 1);      // slot NV = dummy for padded pairs
        nb[oo.x] = ii.x;
        nb[oo.y] = ii.y;
        nb[oo.z] = ii.z;
        nb[oo.w] = ii.w;
    }
}

// ---- main gather-GEMM kernel -------------------------------------------
// block = 256 thr, 4 waves 2x2 (wave = 64 rows x 64 cols): each af LDS read
// feeds 4 MFMAs -> 16 ds_read_b128/wave/offset (half of R5's dominant pipe).
// A: LDS double-buffered (2x32 KB), staged for k+1 before compute(k) so the
// barrier's vmcnt(0) drain overlaps MFMA (R5's proven pipeline). B: full
// per-offset double-buffer in registers (bb0/bb1, 32 uint4), loaded in the
// staging phase; manual unroll-by-2 of the k-loop makes every buffer index a
// literal -> no array copies -> no allocator demotion (the R6 failure).
// ONE barrier per offset.
__global__ __launch_bounds__(256, 2)
void sp_conv_main(const __hip_bfloat16* __restrict__ feats,
                  const uint4* __restrict__ wfrag,
                  const int* __restrict__ nbr,
                  const float* __restrict__ bias,
                  float* __restrict__ out) {
    __shared__ unsigned char smem[65536];   // two 32 KB A buffers

    const int t   = threadIdx.x;
    const int bid = blockIdx.x;
    // XCD swizzle: consecutive 64-tile ranges per XCD for L2 gather locality
    const int tile0 = ((bid & 7) * 64 + (bid >> 3)) * 128;

    const int w    = t >> 6;
    const int lane = t & 63;
    const int lr   = lane & 15;
    const int quad = lane >> 4;
    const int m0   = (w >> 1) * 64;
    const int n0   = (w & 1) * 64;

    // staging-side mapping: LDS slot (row = i*16 + t/16, physchunk = t&15)
    // holds global 16B chunk c = (t&15) ^ (row&15)
    const int srow   = t >> 4;
    const int sbyte  = ((t & 15) ^ srow) * 16;

    f32x4 acc[4][4] = {};  // 64 VGPRs

    const unsigned char* featsB = (const unsigned char*)feats;
    const uint4* wfp = wfrag + (w & 1) * 256 + lane;

    uint4 bb0[4][4], bb1[4][4];
    int arows[8];

    // ---- prologue: nbr(0), stage A0 -> buf0, arows <- nbr(1), bb0 <- B(0)
    {
        const int* nbr0 = nbr + tile0;
        #pragma unroll
        for (int i = 0; i < 8; ++i) arows[i] = nbr0[i * 16 + srow];
    }
    #pragma unroll
    for (int i = 0; i < 8; ++i) {
        unsigned ar = min((unsigned)arows[i], (unsigned)NV);
        async_copy16(smem + i * 4096 + t * 16,
                     featsB + (size_t)ar * 256 + sbyte);
    }
    {
        const int* nbr1 = nbr + (NV + 1) + tile0;
        #pragma unroll
        for (int i = 0; i < 8; ++i) arows[i] = nbr1[i * 16 + srow];
    }
    #pragma unroll
    for (int ks = 0; ks < 4; ++ks)
        #pragma unroll
        for (int nt = 0; nt < 4; ++nt)
            bb0[ks][nt] = wfp[(size_t)ks * 512 + nt * 64];
    __syncthreads();   // A0 staged (vmcnt drain)

// BODY(K, PBUF, CUR, NXT): stage A(K+1)->buf PBUF^1, arows<-nbr(K+2),
// NXT<-B(K+1); compute offset K on buf PBUF with CUR; barrier.
#define BODY(K, PBUF, CUR, NXT)                                               \
    do {                                                                      \
        if ((K) + 1 < KOFF) {                                                 \
            unsigned char* dst = smem + ((PBUF) ^ 1) * 32768;                 \
            _Pragma("unroll")                                                 \
            for (int i = 0; i < 8; ++i) {                                     \
                unsigned ar = min((unsigned)arows[i], (unsigned)NV);          \
                async_copy16(dst + i * 4096 + t * 16,                         \
                             featsB + (size_t)ar * 256 + sbyte);              \
            }                                                                 \
            if ((K) + 2 < KOFF) {                                             \
                const int* nbrn = nbr + ((K) + 2) * (NV + 1) + tile0;         \
                _Pragma("unroll")                                             \
                for (int i = 0; i < 8; ++i) arows[i] = nbrn[i * 16 + srow];   \
            }                                                                 \
            const uint4* wfn = wfp + (size_t)((K) + 1) * 2048;                \
            _Pragma("unroll")                                                 \
            for (int ks = 0; ks < 4; ++ks)                                    \
                _Pragma("unroll")                                             \
                for (int nt = 0; nt < 4; ++nt)                                \
                    NXT[ks][nt] = wfn[(size_t)ks * 512 + nt * 64];            \
        }                                                                     \
        const unsigned char* base = smem + (PBUF) * 32768;                    \
        _Pragma("unroll")                                                     \
        for (int ks = 0; ks < 4; ++ks) {                                      \
            _Pragma("unroll")                                                 \
            for (int mt = 0; mt < 4; ++mt) {                                  \
                int row = m0 + mt * 16 + lr;                                  \
                bf16x8 af = *(const bf16x8*)(base + row * 256 +               \
                                             (((ks * 4 + quad) ^ lr) * 16));  \
                _Pragma("unroll")                                             \
                for (int nt = 0; nt < 4; ++nt)                                \
                    acc[mt][nt] = __builtin_amdgcn_mfma_f32_16x16x32_bf16(    \
                        af, *(const bf16x8*)&CUR[ks][nt],                     \
                        acc[mt][nt], 0, 0, 0);                                \
            }                                                                 \
        }                                                                     \
        __syncthreads();                                                      \
    } while (0)

    for (int kk = 0; kk < KOFF - 1; kk += 2) {
        BODY(kk,     0, bb0, bb1);
        BODY(kk + 1, 1, bb1, bb0);
    }
    BODY(KOFF - 1, 0, bb0, bb1);   // k = 26
#undef BODY

    // epilogue: C/D layout col = lane&15, row = quad*4 + reg
    float bv[4];
    #pragma unroll
    for (int nt = 0; nt < 4; ++nt) bv[nt] = bias[n0 + nt * 16 + lr];

    #pragma unroll
    for (int mt = 0; mt < 4; ++mt) {
        #pragma unroll
        for (int nt = 0; nt < 4; ++nt) {
            #pragma unroll
            for (int r = 0; r < 4; ++r) {
                int grow = tile0 + m0 + mt * 16 + quad * 4 + r;
                out[(size_t)grow * COUT + n0 + nt * 16 + lr] =
                    acc[mt][nt][r] + bv[nt];
            }
        }
    }
}

// ---- launch -------------------------------------------------------------

extern "C" void kernel_launch(void* const* d_in, const int* in_sizes, int n_in,
                              void* d_out, int out_size, void* d_ws, size_t ws_size,
                              hipStream_t stream) {
    const float* features = (const float*)d_in[0];   // [N,128] f32
    const float* weight   = (const float*)d_in[1];   // [27,128,128] f32
    const float* bias     = (const float*)d_in[2];   // [128] f32
    const int*   in_idx   = (const int*)d_in[3];     // [27,N] i32
    const int*   out_idx  = (const int*)d_in[4];     // [27,N] i32
    float* out = (float*)d_out;                      // [N,128] f32

    uint8_t* ws = (uint8_t*)d_ws;
    size_t off = 0;
    __hip_bfloat16* feats_bf = (__hip_bfloat16*)(ws + off);       // (N+1)*128*2
    off += (size_t)(NV + 1) * CIN * 2;
    off = (off + 255) & ~(size_t)255;
    uint4* wfrag = (uint4*)(ws + off);                            // 108*512*16 B
    off += (size_t)108 * 512 * 16;
    off = (off + 255) & ~(size_t)255;
    int* nbr = (int*)(ws + off);                                  // 27*(NV+1)*4

    // init nbr to 0xFFFFFFFF (-1 = "no neighbor"; main clamps to zero row)
    hipMemsetAsync(nbr, 0xFF, (size_t)KOFF * (NV + 1) * 4, stream);

    // fused prep: feature cast + weight fragment-permute + rulebook scatter
    k_prep_all<<<JOB_A_BLOCKS + JOB_B_BLOCKS + JOB_S_BLOCKS, 256, 0, stream>>>(
        features, (uint4*)feats_bf, weight, wfrag,
        (const int4*)in_idx, (const int4*)out_idx, nbr);

    // main gather-GEMM: 512 tiles of 128 rows
    sp_conv_main<<<NV / 128, 256, 0, stream>>>(feats_bf, wfrag, nbr, bias, out);
}